// Round 9
// baseline (389.887 us; speedup 1.0000x reference)
//
#include <hip/hip_runtime.h>
#include <hip/hip_bf16.h>

#define D_MODEL 1024
#define N_HEAD  16
#define HD      64
#define T_SEQ   2048
#define B_SZ    4
#define M_ROWS  (B_SZ * T_SEQ)   // 8192

typedef __bf16 bf16;
typedef __bf16 bf16x4 __attribute__((ext_vector_type(4)));
typedef __bf16 bf16x8 __attribute__((ext_vector_type(8)));
typedef float  floatx4 __attribute__((ext_vector_type(4)));

__device__ __forceinline__ floatx4 fzero4() {
    floatx4 z = {0.f, 0.f, 0.f, 0.f};
    return z;
}

__device__ __forceinline__ bf16x8 cvt8(const float4 a, const float4 b) {
    bf16x8 o;
    o[0] = (bf16)a.x; o[1] = (bf16)a.y; o[2] = (bf16)a.z; o[3] = (bf16)a.w;
    o[4] = (bf16)b.x; o[5] = (bf16)b.y; o[6] = (bf16)b.z; o[7] = (bf16)b.w;
    return o;
}

// async global->LDS, 16B/lane. LDS dest = wave-uniform base + lane*16.
__device__ __forceinline__ void async_ld16(const void* g, void* l) {
    __builtin_amdgcn_global_load_lds(
        (const __attribute__((address_space(1))) void*)g,
        (__attribute__((address_space(3))) void*)l,
        16, 0, 0);
}

// tiny fp32->bf16 convert for the 4 weight matrices only (4 MB each fp32)
struct CvtWArgs {
    const float* s[4];
    bf16* d[4];
};
__global__ __launch_bounds__(256) void cvtw_kernel(CvtWArgs a)
{
    const float* src = a.s[blockIdx.y];
    bf16* dst = a.d[blockIdx.y];
    const int n8 = D_MODEL * D_MODEL / 8;   // 131072
    int i = blockIdx.x * blockDim.x + threadIdx.x;
    int stride = gridDim.x * blockDim.x;
    for (; i < n8; i += stride) {
        float4 x = ((const float4*)src)[2 * i];
        float4 y = ((const float4*)src)[2 * i + 1];
        ((bf16x8*)dst)[i] = cvt8(x, y);
    }
}

struct GemmArgs {
    const void* A[3];     // fp32 (AF32=1) or bf16 (AF32=0), [M,1024]
    const bf16* W[3];     // bf16 [N=1024,K=1024] (nn.Linear weight, row = out-feature)
    const float* bias[3];
    void*       Out[3];
    float       scl[3];
    int         omode[3]; // 0: bf16 [B,H,T,64]; 1: bf16 [B,H,64,T]; 2: fp32 [M,N]
};

// C[8192,1024] = (A @ W^T + bias) * scl.
// Round-9: round-8's 256x128/512-thread tile (verified: gemms dropped below attn)
// + round-5's PROVEN staging (fp32 A reg-staged with fused cvt; W double-buffered
// gload_lds prefetch, latency hidden under MFMA) -> kills the q/k/v fp32->bf16
// HBM round-trip (96 MB read + 48 write + 48 re-read) and merges QKV into ONE
// dispatch (no more Qb/Kb aliasing hazard since A reads the fp32 inputs direct).
//  - Grid (32,8,z): A-sharing blocks same XCD (ids differ by 32 = 0 mod 8).
//  - launch_bounds(512,4): VGPR cap 128 (need ~120: 64 acc + 32 A-staging + addr),
//    2 blocks/CU at 64 KB LDS.
template <int AF32>
__global__ __launch_bounds__(512, 4) void gemm_k(GemmArgs g)
{
    __shared__ bf16 ldsA[256 * 64];       // 32 KB
    __shared__ bf16 ldsW[2][128 * 64];    // 32 KB double-buffered

    const int z = blockIdx.z;
    const bf16* W     = g.W[z];
    const float* bias = g.bias[z];
    void* Out         = g.Out[z];
    const float scl   = g.scl[z];
    const int omode   = g.omode[z];

    const int tid  = threadIdx.x;
    const int wave = tid >> 6, lane = tid & 63;   // wave 0..7
    const int quad = lane >> 4, l15 = lane & 15;
    const int wr = wave >> 1, wc = wave & 1;      // 4 x 2 wave grid
    const int m0 = blockIdx.x * 256, n0 = blockIdx.y * 128;

    floatx4 acc[4][4];
#pragma unroll
    for (int i = 0; i < 4; ++i)
#pragma unroll
        for (int j = 0; j < 4; ++j) acc[i][j] = fzero4();

    const int ro = lane >> 3;   // row-within-8
    const int c8 = lane & 7;    // chunk index

    // A: linear global read (fp32 or bf16), ds_write to XOR-swizzled slot c8^ro
    bf16* dA = &ldsA[(wave * 32 + ro) * 64 + (c8 ^ ro) * 8];
    const float* gAf = nullptr;
    const bf16*  gAb = nullptr;
    if constexpr (AF32)
        gAf = (const float*)g.A[z] + (size_t)(m0 + wave * 32 + ro) * 1024 + c8 * 8;
    else
        gAb = (const bf16*)g.A[z] + (size_t)(m0 + wave * 32 + ro) * 1024 + c8 * 8;

    // W: gload_lds, source pre-swizzled so linear dest realizes slot c = chunk c^ro
    const bf16* gW = W + (size_t)(n0 + wave * 16 + ro) * 1024 + (c8 ^ ro) * 8;

    float4 raf[4][2];
    bf16x8 rab[4];

    // prologue: kt=0 staging issues (latency exposed once)
#pragma unroll
    for (int j = 0; j < 2; ++j)
        async_ld16((const void*)(gW + (size_t)j * 8 * 1024), &ldsW[0][(wave * 16 + j * 8) * 64]);
#pragma unroll
    for (int j = 0; j < 4; ++j) {
        if constexpr (AF32) {
            raf[j][0] = *(const float4*)(gAf + (size_t)j * 8192);
            raf[j][1] = *(const float4*)(gAf + (size_t)j * 8192 + 4);
        } else {
            rab[j] = *(const bf16x8*)(gAb + (size_t)j * 8192);
        }
    }

    for (int kt = 0; kt < 16; ++kt) {
        const int cur = kt & 1;
        __syncthreads();   // drains vmcnt: A regs ready, W[cur] resident; prev LDS reads done
#pragma unroll
        for (int j = 0; j < 4; ++j) {
            if constexpr (AF32)
                *(bf16x8*)(dA + j * 8 * 64) = cvt8(raf[j][0], raf[j][1]);
            else
                *(bf16x8*)(dA + j * 8 * 64) = rab[j];
        }
        __syncthreads();   // staged A visible (W[cur] visible since barrier-1)

        // prefetch kt+1 (issued after the vmcnt-draining barrier so it survives;
        // completes under the MFMA phase, drained at next iteration's barrier-1)
        if (kt < 15) {
            const int off = (kt + 1) * 64;
#pragma unroll
            for (int j = 0; j < 2; ++j)
                async_ld16((const void*)(gW + off + (size_t)j * 8 * 1024),
                           &ldsW[cur ^ 1][(wave * 16 + j * 8) * 64]);
#pragma unroll
            for (int j = 0; j < 4; ++j) {
                if constexpr (AF32) {
                    raf[j][0] = *(const float4*)(gAf + off + (size_t)j * 8192);
                    raf[j][1] = *(const float4*)(gAf + off + (size_t)j * 8192 + 4);
                } else {
                    rab[j] = *(const bf16x8*)(gAb + off + (size_t)j * 8192);
                }
            }
        }

        const bf16* wcur = ldsW[cur];
#pragma unroll
        for (int ks = 0; ks < 2; ++ks) {
            const int pos = ((ks * 4 + quad) ^ (l15 & 7)) * 8;
            bf16x8 af[4], bw[4];
#pragma unroll
            for (int i = 0; i < 4; ++i)
                af[i] = *(const bf16x8*)(&ldsA[(wr * 64 + i * 16 + l15) * 64 + pos]);
#pragma unroll
            for (int j = 0; j < 4; ++j)
                bw[j] = *(const bf16x8*)(&wcur[(wc * 64 + j * 16 + l15) * 64 + pos]);
#pragma unroll
            for (int i = 0; i < 4; ++i)
#pragma unroll
                for (int j = 0; j < 4; ++j)
                    acc[i][j] = __builtin_amdgcn_mfma_f32_16x16x32_bf16(af[i], bw[j], acc[i][j], 0, 0, 0);
        }
    }

    // epilogue
#pragma unroll
    for (int i = 0; i < 4; ++i) {
#pragma unroll
        for (int j = 0; j < 4; ++j) {
            if (omode == 1) {
                // V^T out [B,H,64,T]: r -> t is contiguous; pack bf16x4 (8B stores)
                int m = m0 + wr * 64 + i * 16 + quad * 4;   // r=0
                int n = n0 + wc * 64 + j * 16 + l15;
                int b = m >> 11, t0 = m & 2047;
                int h = n >> 6,  d = n & 63;
                bf16x4 pv;
#pragma unroll
                for (int r = 0; r < 4; ++r)
                    pv[r] = (bf16)((acc[i][j][r] + bias[n]) * scl);
                size_t addr = ((size_t)(b * N_HEAD + h) * HD + d) * T_SEQ + t0;
                *(bf16x4*)(&((bf16*)Out)[addr]) = pv;
            } else {
#pragma unroll
                for (int r = 0; r < 4; ++r) {
                    int m = m0 + wr * 64 + i * 16 + quad * 4 + r;
                    int n = n0 + wc * 64 + j * 16 + l15;
                    float val = (acc[i][j][r] + bias[n]) * scl;
                    if (omode == 2) {
                        ((float*)Out)[(size_t)m * 1024 + n] = val;
                    } else {
                        int b = m >> 11, t = m & 2047;
                        int h = n >> 6,  d = n & 63;
                        size_t addr = ((size_t)(b * N_HEAD + h) * T_SEQ + t) * HD + d;
                        ((bf16*)Out)[addr] = (bf16)val;
                    }
                }
            }
        }
    }
}

// Flash-style causal attention, S^T formulation, paired q-tiles for perfect balance.
// Qh (pre-scaled by 1/8*log2e), Kh: [B,H,T,64] bf16.  Vt: [B,H,64,T] bf16.  AO: [B,T,D] bf16.
// T14 async-STAGE split + T5 setprio + T13 defer-max (verified round 1: 110.9->91.5 us).
__global__ __launch_bounds__(256, 2) void attn_kernel(
    const bf16* __restrict__ Qh, const bf16* __restrict__ Kh,
    const bf16* __restrict__ Vt, bf16* __restrict__ AO)
{
    __shared__ bf16 Ks[128 * 64];   // 16 KB, XOR-swizzled chunks (slot c holds chunk c^(r&7))
    __shared__ bf16 Vts[64 * 128];  // 16 KB, XOR-swizzled (slot c holds chunk c^(d&15))
    __shared__ bf16 Ps[128 * 72];   // 18 KB, half-k P buffer (2-pass), wave-private rows

    const int tid  = threadIdx.x;
    const int wave = tid >> 6, lane = tid & 63;
    const int quad = lane >> 4, l15 = lane & 15;
    const int bh = blockIdx.y;
    const size_t base = (size_t)bh * T_SEQ * HD;
    const int bb = bh >> 4, hh = bh & 15;

    // staging lane->addr precompute (global source pre-swizzled, LDS dest swizzled slot)
    const int kro = lane >> 3;
    const int kgc = (lane & 7) ^ kro;
    const bf16* kgbase = Kh + base + (size_t)(wave * 32 + kro) * HD + kgc * 8;
    const int vrow_lo = lane >> 4;
    const int vchunk  = lane & 15;

    const bf16* vgbase[4];
    bf16* kdst[4];
    bf16* vdst[4];
#pragma unroll
    for (int j = 0; j < 4; ++j) {
        int d = wave * 16 + j * 4 + vrow_lo;
        int gcv = vchunk ^ (d & 15);
        vgbase[j] = Vt + base + (size_t)d * T_SEQ + gcv * 8;
        vdst[j]   = &Vts[d * 128 + vchunk * 8];
        kdst[j]   = &Ks[(wave * 32 + j * 8 + kro) * 64 + (lane & 7) * 8];
    }

    for (int phase = 0; phase < 2; ++phase) {
        const int qt = phase ? blockIdx.x : 15 - blockIdx.x;

        // Q fragments (pre-scaled), B-operand layout: lane l15 = q, k = quad*8+j
        bf16x8 qf[2][2];
        const bf16* qbase = Qh + base + (size_t)(qt * 128 + wave * 32) * HD;
#pragma unroll
        for (int ti = 0; ti < 2; ++ti)
#pragma unroll
            for (int ks = 0; ks < 2; ++ks)
                qf[ti][ks] = *(const bf16x8*)(qbase + (ti * 16 + l15) * HD + ks * 32 + quad * 8);

        // prologue: issue reg-loads for kt=0 (latency exposed once per phase)
        bf16x8 kreg[4], vreg[4];
#pragma unroll
        for (int j = 0; j < 4; ++j)
            kreg[j] = *(const bf16x8*)(kgbase + (size_t)(j * 8) * HD);
#pragma unroll
        for (int j = 0; j < 4; ++j)
            vreg[j] = *(const bf16x8*)(vgbase[j]);

        float mrow[2] = {-1e30f, -1e30f}, lrow[2] = {0.f, 0.f};
        floatx4 oacc[2][4];
#pragma unroll
        for (int ti = 0; ti < 2; ++ti)
#pragma unroll
            for (int nj = 0; nj < 4; ++nj) oacc[ti][nj] = fzero4();

        for (int kt = 0; kt <= qt; ++kt) {
            __syncthreads();   // all waves done reading Ks/Vts; vmcnt drain -> kreg/vreg ready
#pragma unroll
            for (int j = 0; j < 4; ++j) *(bf16x8*)kdst[j] = kreg[j];
#pragma unroll
            for (int j = 0; j < 4; ++j) *(bf16x8*)vdst[j] = vreg[j];
            __syncthreads();   // staged tile visible

            // T14: issue next tile's loads NOW; they complete under the compute below
            if (kt < qt) {
#pragma unroll
                for (int j = 0; j < 4; ++j)
                    kreg[j] = *(const bf16x8*)(kgbase + (size_t)((kt + 1) * 128 + j * 8) * HD);
#pragma unroll
                for (int j = 0; j < 4; ++j)
                    vreg[j] = *(const bf16x8*)(vgbase[j] + (kt + 1) * 128);
            }

            const bool diag = (kt == qt);
            const int lim = diag ? (2 * wave + 1) : 7;   // max tj with any unmasked k

            // S^T = K Q^T : A = K-frag (l15 = k-row), B = Q-frag (l15 = q)
            floatx4 sacc[2][8];
#pragma unroll
            for (int ti = 0; ti < 2; ++ti)
#pragma unroll
                for (int tj = 0; tj < 8; ++tj) sacc[ti][tj] = fzero4();
            __builtin_amdgcn_s_setprio(1);
#pragma unroll
            for (int ks = 0; ks < 2; ++ks) {
                const int pos = ((ks * 4 + quad) ^ (l15 & 7)) * 8;
#pragma unroll
                for (int tj = 0; tj < 8; ++tj) {
                    if (tj <= lim) {
                        bf16x8 kf = *(const bf16x8*)(&Ks[(tj * 16 + l15) * 64 + pos]);
                        sacc[0][tj] = __builtin_amdgcn_mfma_f32_16x16x32_bf16(kf, qf[0][ks], sacc[0][tj], 0, 0, 0);
                        sacc[1][tj] = __builtin_amdgcn_mfma_f32_16x16x32_bf16(kf, qf[1][ks], sacc[1][tj], 0, 0, 0);
                    }
                }
            }
            __builtin_amdgcn_s_setprio(0);

            // online softmax (scores pre-scaled): lane owns q = l15 (per ti)
#pragma unroll
            for (int ti = 0; ti < 2; ++ti) {
                const int ql = wave * 32 + ti * 16 + l15;
                float mxp[4] = {-1e30f, -1e30f, -1e30f, -1e30f};
#pragma unroll
                for (int tj = 0; tj < 8; ++tj) {
                    if (tj <= lim) {
#pragma unroll
                        for (int r = 0; r < 4; ++r) {
                            float s = sacc[ti][tj][r];
                            if (diag && (tj * 16 + quad * 4 + r) > ql) s = -1e30f;
                            sacc[ti][tj][r] = s;
                            mxp[r] = fmaxf(mxp[r], s);
                        }
                    }
                }
                float mx = fmaxf(fmaxf(mxp[0], mxp[1]), fmaxf(mxp[2], mxp[3]));
                mx = fmaxf(mx, __shfl_xor(mx, 16));
                mx = fmaxf(mx, __shfl_xor(mx, 32));
                // T13 defer-max: only rescale when some row's max grew by >8 (log2)
                if (__any(mx > mrow[ti] + 8.0f)) {
                    float mnew  = fmaxf(mrow[ti], mx);
                    float alpha = exp2f(mrow[ti] - mnew);
                    mrow[ti] = mnew;
                    lrow[ti] *= alpha;
#pragma unroll
                    for (int r = 0; r < 4; ++r) {
                        float ar = __shfl(alpha, quad * 4 + r);
#pragma unroll
                        for (int nj = 0; nj < 4; ++nj)
                            oacc[ti][nj][r] *= ar;
                    }
                }
                float rs[4] = {0.f, 0.f, 0.f, 0.f};
#pragma unroll
                for (int tj = 0; tj < 8; ++tj) {
                    if (tj <= lim) {
#pragma unroll
                        for (int r = 0; r < 4; ++r) {
                            float p = exp2f(sacc[ti][tj][r] - mrow[ti]);
                            rs[r] += p;
                            sacc[ti][tj][r] = p;
                        }
                    }
                }
                float rsum = (rs[0] + rs[1]) + (rs[2] + rs[3]);
                rsum += __shfl_xor(rsum, 16);
                rsum += __shfl_xor(rsum, 32);
                lrow[ti] += rsum;
            }

            // P -> LDS and O += P V, in two k-halves (Ps wave-private rows)
#pragma unroll
            for (int h2 = 0; h2 < 2; ++h2) {
                if (4 * h2 > lim) break;
#pragma unroll
                for (int ti = 0; ti < 2; ++ti) {
                    const int ql = wave * 32 + ti * 16 + l15;
#pragma unroll
                    for (int tjo = 0; tjo < 4; ++tjo) {
                        int tj = 4 * h2 + tjo;
                        if (tj <= lim) {
                            bf16x4 pv;
#pragma unroll
                            for (int r = 0; r < 4; ++r) pv[r] = (bf16)sacc[ti][tj][r];
                            *(bf16x4*)(&Ps[ql * 72 + tjo * 16 + quad * 4]) = pv;
                        }
                    }
                }
#pragma unroll
                for (int ks2 = 0; ks2 < 2; ++ks2) {
                    const int gks = 2 * h2 + ks2;
                    if (diag && gks > wave) break;
                    bf16x8 pf[2];
                    pf[0] = *(const bf16x8*)(&Ps[(wave * 32 + l15) * 72 + ks2 * 32 + quad * 8]);
                    pf[1] = *(const bf16x8*)(&Ps[(wave * 32 + 16 + l15) * 72 + ks2 * 32 + quad * 8]);
                    __builtin_amdgcn_s_setprio(1);
#pragma unroll
                    for (int nj = 0; nj < 4; ++nj) {
                        int pos = ((gks * 4 + quad) ^ l15) * 8;
                        bf16x8 vf = *(const bf16x8*)(&Vts[(nj * 16 + l15) * 128 + pos]);
                        oacc[0][nj] = __builtin_amdgcn_mfma_f32_16x16x32_bf16(pf[0], vf, oacc[0][nj], 0, 0, 0);
                        oacc[1][nj] = __builtin_amdgcn_mfma_f32_16x16x32_bf16(pf[1], vf, oacc[1][nj], 0, 0, 0);
                    }
                    __builtin_amdgcn_s_setprio(0);
                }
            }
        }

        // epilogue: O /= l ; O rows = quad*4+r, cols d = nj*16+l15
#pragma unroll
        for (int ti = 0; ti < 2; ++ti) {
#pragma unroll
            for (int r = 0; r < 4; ++r) {
                float lv = __shfl(lrow[ti], quad * 4 + r);
                float rl = 1.f / lv;
                int qrow = qt * 128 + wave * 32 + ti * 16 + quad * 4 + r;
#pragma unroll
                for (int nj = 0; nj < 4; ++nj) {
                    int d = nj * 16 + l15;
                    AO[((size_t)(bb * T_SEQ + qrow)) * D_MODEL + hh * HD + d] =
                        (bf16)(oacc[ti][nj][r] * rl);
                }
            }
        }
    }
}

extern "C" void kernel_launch(void* const* d_in, const int* in_sizes, int n_in,
                              void* d_out, int out_size, void* d_ws, size_t ws_size,
                              hipStream_t stream)
{
    const float* q  = (const float*)d_in[0];
    const float* k  = (const float*)d_in[1];
    const float* v  = (const float*)d_in[2];
    const float* wq = (const float*)d_in[3];
    const float* bq = (const float*)d_in[4];
    const float* wk = (const float*)d_in[5];
    const float* bk = (const float*)d_in[6];
    const float* wv = (const float*)d_in[7];
    const float* bv = (const float*)d_in[8];
    const float* wo = (const float*)d_in[9];
    const float* bo = (const float*)d_in[10];

    char* ws  = (char*)d_ws;
    char* dob = (char*)d_out;
    const size_t MB = 1024 * 1024;

    // ws: Wqb[0,2) Wkb[2,4) Wvb[4,6) Wob[6,8) AO[8,24) Qh[24,40) Kh[40,56)
    // d_out (32 MB): Vt[0,16) bf16 during QKV+attn, then final fp32 out (O-gemm
    // overwrites after attn has consumed Vt).
    bf16* Wqb = (bf16*)(ws);
    bf16* Wkb = (bf16*)(ws + 2 * MB);
    bf16* Wvb = (bf16*)(ws + 4 * MB);
    bf16* Wob = (bf16*)(ws + 6 * MB);
    bf16* AO  = (bf16*)(ws + 8 * MB);
    bf16* Qh  = (bf16*)(ws + 24 * MB);
    bf16* Kh  = (bf16*)(ws + 40 * MB);
    bf16* Vt  = (bf16*)(dob);

    const float QSCALE = 0.18033688011112042f;  // (1/sqrt(64)) * log2(e)

    CvtWArgs cw;
    cw.s[0] = wq; cw.d[0] = Wqb;
    cw.s[1] = wk; cw.d[1] = Wkb;
    cw.s[2] = wv; cw.d[2] = Wvb;
    cw.s[3] = wo; cw.d[3] = Wob;

    GemmArgs gq;
    gq.A[0] = q; gq.W[0] = Wqb; gq.bias[0] = bq; gq.Out[0] = (void*)Qh; gq.scl[0] = QSCALE; gq.omode[0] = 0;
    gq.A[1] = k; gq.W[1] = Wkb; gq.bias[1] = bk; gq.Out[1] = (void*)Kh; gq.scl[1] = 1.0f;   gq.omode[1] = 0;
    gq.A[2] = v; gq.W[2] = Wvb; gq.bias[2] = bv; gq.Out[2] = (void*)Vt; gq.scl[2] = 1.0f;   gq.omode[2] = 1;

    GemmArgs go;
    go.A[0] = AO; go.W[0] = Wob; go.bias[0] = bo; go.Out[0] = d_out; go.scl[0] = 1.0f; go.omode[0] = 2;
    go.A[1] = AO; go.W[1] = Wob; go.bias[1] = bo; go.Out[1] = d_out; go.scl[1] = 1.0f; go.omode[1] = 2;
    go.A[2] = AO; go.W[2] = Wob; go.bias[2] = bo; go.Out[2] = d_out; go.scl[2] = 1.0f; go.omode[2] = 2;

    hipLaunchKernelGGL(cvtw_kernel, dim3(64, 4), dim3(256), 0, stream, cw);
    hipLaunchKernelGGL((gemm_k<1>), dim3(32, 8, 3), dim3(512), 0, stream, gq);
    hipLaunchKernelGGL(attn_kernel, dim3(8, 64), dim3(256), 0, stream, Qh, Kh, Vt, AO);
    hipLaunchKernelGGL((gemm_k<0>), dim3(32, 8, 1), dim3(512), 0, stream, go);
}

// Round 10
// 360.571 us; speedup vs baseline: 1.0813x; 1.0813x over previous
//
#include <hip/hip_runtime.h>
#include <hip/hip_bf16.h>

#define D_MODEL 1024
#define N_HEAD  16
#define HD      64
#define T_SEQ   2048
#define B_SZ    4
#define M_ROWS  (B_SZ * T_SEQ)   // 8192

typedef __bf16 bf16;
typedef __bf16 bf16x4 __attribute__((ext_vector_type(4)));
typedef __bf16 bf16x8 __attribute__((ext_vector_type(8)));
typedef float  floatx4 __attribute__((ext_vector_type(4)));

__device__ __forceinline__ floatx4 fzero4() {
    floatx4 z = {0.f, 0.f, 0.f, 0.f};
    return z;
}

__device__ __forceinline__ bf16x8 cvt8(const float4 a, const float4 b) {
    bf16x8 o;
    o[0] = (bf16)a.x; o[1] = (bf16)a.y; o[2] = (bf16)a.z; o[3] = (bf16)a.w;
    o[4] = (bf16)b.x; o[5] = (bf16)b.y; o[6] = (bf16)b.z; o[7] = (bf16)b.w;
    return o;
}

// async global->LDS, 16B/lane. LDS dest = wave-uniform base + lane*16.
__device__ __forceinline__ void async_ld16(const void* g, void* l) {
    __builtin_amdgcn_global_load_lds(
        (const __attribute__((address_space(1))) void*)g,
        (__attribute__((address_space(3))) void*)l,
        16, 0, 0);
}

// fused fp32 -> bf16 convert: 6 segments (q, k + 4 weights). v is consumed
// as fp32 directly by the V slice of the QKV GEMM (reg-staged cvt).
struct CvtArgs {
    const float* s[6];
    bf16* d[6];
    int n[6];
};
__global__ __launch_bounds__(256) void cvt6_kernel(CvtArgs a)
{
    const float* src = a.s[blockIdx.y];
    bf16* dst = a.d[blockIdx.y];
    int n8 = a.n[blockIdx.y];
    int i = blockIdx.x * blockDim.x + threadIdx.x;
    int stride = gridDim.x * blockDim.x;
    for (; i < n8; i += stride) {
        float4 x = ((const float4*)src)[2 * i];
        float4 y = ((const float4*)src)[2 * i + 1];
        ((bf16x8*)dst)[i] = cvt8(x, y);
    }
}

struct GemmArgs {
    const void* A[3];     // bf16 (af32=0) or fp32 (af32=1), [M,1024]
    const bf16* W[3];     // bf16 [N=1024,K=1024] (nn.Linear weight, row = out-feature)
    const float* bias[3];
    void*       Out[3];
    float       scl[3];
    int         omode[3]; // 0: bf16 [B,H,T,64]; 1: bf16 [B,H,64,T]; 2: fp32 [M,N]
    int         af32[3];  // 1: A is fp32, reg-staged with fused cvt
};

// C[8192,1024] = (A @ W^T + bias) * scl.
// Round-10 = round-8's PROVEN structure (best: 351.7 us) + per-slice af32:
//  - 256x128 tile, 512 threads (8 waves, 4x2), single-buffered LDS,
//    2x __syncthreads per K-step.
//  - af32=0 slices (Q,K,O): A staged via global_load_lds, pre-swizzled source
//    (zero staging VGPRs) -- the R8 path, fastest measured (~46-50 us/slice,
//    and the only structure that held <92 us at 1 block/CU for the O-GEMM;
//    R9's reg-staged O-GEMM collapsed to ~150 us there).
//  - af32=1 slice (V): A read fp32, reg-staged with fused cvt on the ds_write
//    (R5-proven). Runs co-resident with the Q/K slices (768 blocks) so its
//    serial staging hides under the other slices' MFMA.
//  - Grid (32,8,z): A-sharing blocks same XCD (ids differ by 32 = 0 mod 8).
//  - launch_bounds(512,4): VGPR cap 128 (acc in AGPRs; ~96 arch VGPRs), 48 KB LDS.
__global__ __launch_bounds__(512, 4) void gemm_k(GemmArgs g)
{
    __shared__ bf16 ldsA[256 * 64];   // 32 KB
    __shared__ bf16 ldsW[128 * 64];   // 16 KB

    const int z = blockIdx.z;
    const bf16* W     = g.W[z];
    const float* bias = g.bias[z];
    void* Out         = g.Out[z];
    const float scl   = g.scl[z];
    const int omode   = g.omode[z];
    const int af32    = g.af32[z];

    const int tid  = threadIdx.x;
    const int wave = tid >> 6, lane = tid & 63;   // wave 0..7
    const int quad = lane >> 4, l15 = lane & 15;
    const int wr = wave >> 1, wc = wave & 1;      // 4 x 2 wave grid
    const int m0 = blockIdx.x * 256, n0 = blockIdx.y * 128;

    floatx4 acc[4][4];
#pragma unroll
    for (int i = 0; i < 4; ++i)
#pragma unroll
        for (int j = 0; j < 4; ++j) acc[i][j] = fzero4();

    const int ro = lane >> 3;   // row-within-8
    const int c8 = lane & 7;    // chunk index

    // bf16 path: pre-swizzled global source, linear LDS dest (slot c holds chunk c^ro)
    const bf16* gAb = (const bf16*)g.A[z] + (size_t)(m0 + wave * 32 + ro) * 1024 + (c8 ^ ro) * 8;
    // fp32 path: linear global source, swizzled ds_write dest (same final layout)
    const float* gAf = (const float*)g.A[z] + (size_t)(m0 + wave * 32 + ro) * 1024 + c8 * 8;
    bf16* dA = &ldsA[(wave * 32 + ro) * 64 + (c8 ^ ro) * 8];

    const bf16* gW = W + (size_t)(n0 + wave * 16 + ro) * 1024 + (c8 ^ ro) * 8;

    float4 raf[4][2];
    if (af32) {
        // prologue: A(0) reg loads (latency exposed once)
#pragma unroll
        for (int j = 0; j < 4; ++j) {
            raf[j][0] = *(const float4*)(gAf + (size_t)j * 8192);
            raf[j][1] = *(const float4*)(gAf + (size_t)j * 8192 + 4);
        }
    }

    for (int kt = 0; kt < 16; ++kt) {
        __syncthreads();   // b1: prev-tile reads done; (af32: A regs drained by vmcnt(0))
        if (af32) {
#pragma unroll
            for (int j = 0; j < 4; ++j)
                *(bf16x8*)(dA + j * 8 * 64) = cvt8(raf[j][0], raf[j][1]);
        } else {
#pragma unroll
            for (int j = 0; j < 4; ++j)
                async_ld16((const void*)(gAb + kt * 64 + (size_t)j * 8 * 1024),
                           &ldsA[(wave * 32 + j * 8) * 64]);
        }
#pragma unroll
        for (int j = 0; j < 2; ++j)
            async_ld16((const void*)(gW + kt * 64 + (size_t)j * 8 * 1024),
                       &ldsW[(wave * 16 + j * 8) * 64]);
        __syncthreads();   // b2: vmcnt+lgkm drained -> tile visible

        // af32: issue next tile's A reg loads now; in flight under MFMA, drained at next b1
        if (af32 && kt < 15) {
            const int off = (kt + 1) * 64;
#pragma unroll
            for (int j = 0; j < 4; ++j) {
                raf[j][0] = *(const float4*)(gAf + off + (size_t)j * 8192);
                raf[j][1] = *(const float4*)(gAf + off + (size_t)j * 8192 + 4);
            }
        }

#pragma unroll
        for (int ks = 0; ks < 2; ++ks) {
            const int pos = ((ks * 4 + quad) ^ (l15 & 7)) * 8;
            bf16x8 af[4], bw[4];
#pragma unroll
            for (int i = 0; i < 4; ++i)
                af[i] = *(const bf16x8*)(&ldsA[(wr * 64 + i * 16 + l15) * 64 + pos]);
#pragma unroll
            for (int j = 0; j < 4; ++j)
                bw[j] = *(const bf16x8*)(&ldsW[(wc * 64 + j * 16 + l15) * 64 + pos]);
#pragma unroll
            for (int i = 0; i < 4; ++i)
#pragma unroll
                for (int j = 0; j < 4; ++j)
                    acc[i][j] = __builtin_amdgcn_mfma_f32_16x16x32_bf16(af[i], bw[j], acc[i][j], 0, 0, 0);
        }
    }

    // epilogue
#pragma unroll
    for (int i = 0; i < 4; ++i) {
#pragma unroll
        for (int j = 0; j < 4; ++j) {
            if (omode == 1) {
                // V^T out [B,H,64,T]: r -> t is contiguous; pack bf16x4 (8B stores)
                int m = m0 + wr * 64 + i * 16 + quad * 4;   // r=0
                int n = n0 + wc * 64 + j * 16 + l15;
                int b = m >> 11, t0 = m & 2047;
                int h = n >> 6,  d = n & 63;
                bf16x4 pv;
#pragma unroll
                for (int r = 0; r < 4; ++r)
                    pv[r] = (bf16)((acc[i][j][r] + bias[n]) * scl);
                size_t addr = ((size_t)(b * N_HEAD + h) * HD + d) * T_SEQ + t0;
                *(bf16x4*)(&((bf16*)Out)[addr]) = pv;
            } else {
#pragma unroll
                for (int r = 0; r < 4; ++r) {
                    int m = m0 + wr * 64 + i * 16 + quad * 4 + r;
                    int n = n0 + wc * 64 + j * 16 + l15;
                    float val = (acc[i][j][r] + bias[n]) * scl;
                    if (omode == 2) {
                        ((float*)Out)[(size_t)m * 1024 + n] = val;
                    } else {
                        int b = m >> 11, t = m & 2047;
                        int h = n >> 6,  d = n & 63;
                        size_t addr = ((size_t)(b * N_HEAD + h) * T_SEQ + t) * HD + d;
                        ((bf16*)Out)[addr] = (bf16)val;
                    }
                }
            }
        }
    }
}

// Flash-style causal attention, S^T formulation, paired q-tiles for perfect balance.
// Qh (pre-scaled by 1/8*log2e), Kh: [B,H,T,64] bf16.  Vt: [B,H,64,T] bf16.  AO: [B,T,D] bf16.
// T14 async-STAGE split + T5 setprio + T13 defer-max (verified round 1: 110.9->91.5 us).
__global__ __launch_bounds__(256, 2) void attn_kernel(
    const bf16* __restrict__ Qh, const bf16* __restrict__ Kh,
    const bf16* __restrict__ Vt, bf16* __restrict__ AO)
{
    __shared__ bf16 Ks[128 * 64];   // 16 KB, XOR-swizzled chunks (slot c holds chunk c^(r&7))
    __shared__ bf16 Vts[64 * 128];  // 16 KB, XOR-swizzled (slot c holds chunk c^(d&15))
    __shared__ bf16 Ps[128 * 72];   // 18 KB, half-k P buffer (2-pass), wave-private rows

    const int tid  = threadIdx.x;
    const int wave = tid >> 6, lane = tid & 63;
    const int quad = lane >> 4, l15 = lane & 15;
    const int bh = blockIdx.y;
    const size_t base = (size_t)bh * T_SEQ * HD;
    const int bb = bh >> 4, hh = bh & 15;

    // staging lane->addr precompute (global source pre-swizzled, LDS dest swizzled slot)
    const int kro = lane >> 3;
    const int kgc = (lane & 7) ^ kro;
    const bf16* kgbase = Kh + base + (size_t)(wave * 32 + kro) * HD + kgc * 8;
    const int vrow_lo = lane >> 4;
    const int vchunk  = lane & 15;

    const bf16* vgbase[4];
    bf16* kdst[4];
    bf16* vdst[4];
#pragma unroll
    for (int j = 0; j < 4; ++j) {
        int d = wave * 16 + j * 4 + vrow_lo;
        int gcv = vchunk ^ (d & 15);
        vgbase[j] = Vt + base + (size_t)d * T_SEQ + gcv * 8;
        vdst[j]   = &Vts[d * 128 + vchunk * 8];
        kdst[j]   = &Ks[(wave * 32 + j * 8 + kro) * 64 + (lane & 7) * 8];
    }

    for (int phase = 0; phase < 2; ++phase) {
        const int qt = phase ? blockIdx.x : 15 - blockIdx.x;

        // Q fragments (pre-scaled), B-operand layout: lane l15 = q, k = quad*8+j
        bf16x8 qf[2][2];
        const bf16* qbase = Qh + base + (size_t)(qt * 128 + wave * 32) * HD;
#pragma unroll
        for (int ti = 0; ti < 2; ++ti)
#pragma unroll
            for (int ks = 0; ks < 2; ++ks)
                qf[ti][ks] = *(const bf16x8*)(qbase + (ti * 16 + l15) * HD + ks * 32 + quad * 8);

        // prologue: issue reg-loads for kt=0 (latency exposed once per phase)
        bf16x8 kreg[4], vreg[4];
#pragma unroll
        for (int j = 0; j < 4; ++j)
            kreg[j] = *(const bf16x8*)(kgbase + (size_t)(j * 8) * HD);
#pragma unroll
        for (int j = 0; j < 4; ++j)
            vreg[j] = *(const bf16x8*)(vgbase[j]);

        float mrow[2] = {-1e30f, -1e30f}, lrow[2] = {0.f, 0.f};
        floatx4 oacc[2][4];
#pragma unroll
        for (int ti = 0; ti < 2; ++ti)
#pragma unroll
            for (int nj = 0; nj < 4; ++nj) oacc[ti][nj] = fzero4();

        for (int kt = 0; kt <= qt; ++kt) {
            __syncthreads();   // all waves done reading Ks/Vts; vmcnt drain -> kreg/vreg ready
#pragma unroll
            for (int j = 0; j < 4; ++j) *(bf16x8*)kdst[j] = kreg[j];
#pragma unroll
            for (int j = 0; j < 4; ++j) *(bf16x8*)vdst[j] = vreg[j];
            __syncthreads();   // staged tile visible

            // T14: issue next tile's loads NOW; they complete under the compute below
            if (kt < qt) {
#pragma unroll
                for (int j = 0; j < 4; ++j)
                    kreg[j] = *(const bf16x8*)(kgbase + (size_t)((kt + 1) * 128 + j * 8) * HD);
#pragma unroll
                for (int j = 0; j < 4; ++j)
                    vreg[j] = *(const bf16x8*)(vgbase[j] + (kt + 1) * 128);
            }

            const bool diag = (kt == qt);
            const int lim = diag ? (2 * wave + 1) : 7;   // max tj with any unmasked k

            // S^T = K Q^T : A = K-frag (l15 = k-row), B = Q-frag (l15 = q)
            floatx4 sacc[2][8];
#pragma unroll
            for (int ti = 0; ti < 2; ++ti)
#pragma unroll
                for (int tj = 0; tj < 8; ++tj) sacc[ti][tj] = fzero4();
            __builtin_amdgcn_s_setprio(1);
#pragma unroll
            for (int ks = 0; ks < 2; ++ks) {
                const int pos = ((ks * 4 + quad) ^ (l15 & 7)) * 8;
#pragma unroll
                for (int tj = 0; tj < 8; ++tj) {
                    if (tj <= lim) {
                        bf16x8 kf = *(const bf16x8*)(&Ks[(tj * 16 + l15) * 64 + pos]);
                        sacc[0][tj] = __builtin_amdgcn_mfma_f32_16x16x32_bf16(kf, qf[0][ks], sacc[0][tj], 0, 0, 0);
                        sacc[1][tj] = __builtin_amdgcn_mfma_f32_16x16x32_bf16(kf, qf[1][ks], sacc[1][tj], 0, 0, 0);
                    }
                }
            }
            __builtin_amdgcn_s_setprio(0);

            // online softmax (scores pre-scaled): lane owns q = l15 (per ti)
#pragma unroll
            for (int ti = 0; ti < 2; ++ti) {
                const int ql = wave * 32 + ti * 16 + l15;
                float mxp[4] = {-1e30f, -1e30f, -1e30f, -1e30f};
#pragma unroll
                for (int tj = 0; tj < 8; ++tj) {
                    if (tj <= lim) {
#pragma unroll
                        for (int r = 0; r < 4; ++r) {
                            float s = sacc[ti][tj][r];
                            if (diag && (tj * 16 + quad * 4 + r) > ql) s = -1e30f;
                            sacc[ti][tj][r] = s;
                            mxp[r] = fmaxf(mxp[r], s);
                        }
                    }
                }
                float mx = fmaxf(fmaxf(mxp[0], mxp[1]), fmaxf(mxp[2], mxp[3]));
                mx = fmaxf(mx, __shfl_xor(mx, 16));
                mx = fmaxf(mx, __shfl_xor(mx, 32));
                // T13 defer-max: only rescale when some row's max grew by >8 (log2)
                if (__any(mx > mrow[ti] + 8.0f)) {
                    float mnew  = fmaxf(mrow[ti], mx);
                    float alpha = exp2f(mrow[ti] - mnew);
                    mrow[ti] = mnew;
                    lrow[ti] *= alpha;
#pragma unroll
                    for (int r = 0; r < 4; ++r) {
                        float ar = __shfl(alpha, quad * 4 + r);
#pragma unroll
                        for (int nj = 0; nj < 4; ++nj)
                            oacc[ti][nj][r] *= ar;
                    }
                }
                float rs[4] = {0.f, 0.f, 0.f, 0.f};
#pragma unroll
                for (int tj = 0; tj < 8; ++tj) {
                    if (tj <= lim) {
#pragma unroll
                        for (int r = 0; r < 4; ++r) {
                            float p = exp2f(sacc[ti][tj][r] - mrow[ti]);
                            rs[r] += p;
                            sacc[ti][tj][r] = p;
                        }
                    }
                }
                float rsum = (rs[0] + rs[1]) + (rs[2] + rs[3]);
                rsum += __shfl_xor(rsum, 16);
                rsum += __shfl_xor(rsum, 32);
                lrow[ti] += rsum;
            }

            // P -> LDS and O += P V, in two k-halves (Ps wave-private rows)
#pragma unroll
            for (int h2 = 0; h2 < 2; ++h2) {
                if (4 * h2 > lim) break;
#pragma unroll
                for (int ti = 0; ti < 2; ++ti) {
                    const int ql = wave * 32 + ti * 16 + l15;
#pragma unroll
                    for (int tjo = 0; tjo < 4; ++tjo) {
                        int tj = 4 * h2 + tjo;
                        if (tj <= lim) {
                            bf16x4 pv;
#pragma unroll
                            for (int r = 0; r < 4; ++r) pv[r] = (bf16)sacc[ti][tj][r];
                            *(bf16x4*)(&Ps[ql * 72 + tjo * 16 + quad * 4]) = pv;
                        }
                    }
                }
#pragma unroll
                for (int ks2 = 0; ks2 < 2; ++ks2) {
                    const int gks = 2 * h2 + ks2;
                    if (diag && gks > wave) break;
                    bf16x8 pf[2];
                    pf[0] = *(const bf16x8*)(&Ps[(wave * 32 + l15) * 72 + ks2 * 32 + quad * 8]);
                    pf[1] = *(const bf16x8*)(&Ps[(wave * 32 + 16 + l15) * 72 + ks2 * 32 + quad * 8]);
                    __builtin_amdgcn_s_setprio(1);
#pragma unroll
                    for (int nj = 0; nj < 4; ++nj) {
                        int pos = ((gks * 4 + quad) ^ l15) * 8;
                        bf16x8 vf = *(const bf16x8*)(&Vts[(nj * 16 + l15) * 128 + pos]);
                        oacc[0][nj] = __builtin_amdgcn_mfma_f32_16x16x32_bf16(pf[0], vf, oacc[0][nj], 0, 0, 0);
                        oacc[1][nj] = __builtin_amdgcn_mfma_f32_16x16x32_bf16(pf[1], vf, oacc[1][nj], 0, 0, 0);
                    }
                    __builtin_amdgcn_s_setprio(0);
                }
            }
        }

        // epilogue: O /= l ; O rows = quad*4+r, cols d = nj*16+l15
#pragma unroll
        for (int ti = 0; ti < 2; ++ti) {
#pragma unroll
            for (int r = 0; r < 4; ++r) {
                float lv = __shfl(lrow[ti], quad * 4 + r);
                float rl = 1.f / lv;
                int qrow = qt * 128 + wave * 32 + ti * 16 + quad * 4 + r;
#pragma unroll
                for (int nj = 0; nj < 4; ++nj) {
                    int d = nj * 16 + l15;
                    AO[((size_t)(bb * T_SEQ + qrow)) * D_MODEL + hh * HD + d] =
                        (bf16)(oacc[ti][nj][r] * rl);
                }
            }
        }
    }
}

extern "C" void kernel_launch(void* const* d_in, const int* in_sizes, int n_in,
                              void* d_out, int out_size, void* d_ws, size_t ws_size,
                              hipStream_t stream)
{
    const float* q  = (const float*)d_in[0];
    const float* k  = (const float*)d_in[1];
    const float* v  = (const float*)d_in[2];
    const float* wq = (const float*)d_in[3];
    const float* bq = (const float*)d_in[4];
    const float* wk = (const float*)d_in[5];
    const float* bk = (const float*)d_in[6];
    const float* wv = (const float*)d_in[7];
    const float* bv = (const float*)d_in[8];
    const float* wo = (const float*)d_in[9];
    const float* bo = (const float*)d_in[10];

    char* ws  = (char*)d_ws;
    char* dob = (char*)d_out;
    const size_t MB = 1024 * 1024;

    // ws (56 MB): Wqb[0,2) Wkb[2,4) Wvb[4,6) Wob[6,8) Qb[8,24) Kb[24,40) Vt[40,56)
    //   AO overwrites Qb's region [8,24) after the QKV GEMM consumed Qb.
    // d_out (32 MB): Qh[0,16) Kh[16,32) bf16 during attn, then final fp32 out
    //   (O-GEMM overwrites after attn consumed Qh/Kh).
    bf16* Wqb = (bf16*)(ws);
    bf16* Wkb = (bf16*)(ws + 2 * MB);
    bf16* Wvb = (bf16*)(ws + 4 * MB);
    bf16* Wob = (bf16*)(ws + 6 * MB);
    bf16* Qb  = (bf16*)(ws + 8 * MB);
    bf16* AO  = (bf16*)(ws + 8 * MB);
    bf16* Kb  = (bf16*)(ws + 24 * MB);
    bf16* Vt  = (bf16*)(ws + 40 * MB);
    bf16* Qh  = (bf16*)(dob);
    bf16* Kh  = (bf16*)(dob + 16 * MB);

    const int NQ8 = M_ROWS * D_MODEL / 8;   // 1M
    const int NW8 = D_MODEL * D_MODEL / 8;  // 128K
    const float QSCALE = 0.18033688011112042f;  // (1/sqrt(64)) * log2(e)

    CvtArgs ca;
    ca.s[0] = q;  ca.d[0] = Qb;  ca.n[0] = NQ8;
    ca.s[1] = k;  ca.d[1] = Kb;  ca.n[1] = NQ8;
    ca.s[2] = wq; ca.d[2] = Wqb; ca.n[2] = NW8;
    ca.s[3] = wk; ca.d[3] = Wkb; ca.n[3] = NW8;
    ca.s[4] = wv; ca.d[4] = Wvb; ca.n[4] = NW8;
    ca.s[5] = wo; ca.d[5] = Wob; ca.n[5] = NW8;

    GemmArgs gq;
    gq.A[0] = Qb; gq.W[0] = Wqb; gq.bias[0] = bq; gq.Out[0] = (void*)Qh; gq.scl[0] = QSCALE; gq.omode[0] = 0; gq.af32[0] = 0;
    gq.A[1] = Kb; gq.W[1] = Wkb; gq.bias[1] = bk; gq.Out[1] = (void*)Kh; gq.scl[1] = 1.0f;   gq.omode[1] = 0; gq.af32[1] = 0;
    gq.A[2] = v;  gq.W[2] = Wvb; gq.bias[2] = bv; gq.Out[2] = (void*)Vt; gq.scl[2] = 1.0f;   gq.omode[2] = 1; gq.af32[2] = 1;

    GemmArgs go;
    go.A[0] = AO; go.W[0] = Wob; go.bias[0] = bo; go.Out[0] = d_out; go.scl[0] = 1.0f; go.omode[0] = 2; go.af32[0] = 0;
    go.A[1] = AO; go.W[1] = Wob; go.bias[1] = bo; go.Out[1] = d_out; go.scl[1] = 1.0f; go.omode[1] = 2; go.af32[1] = 0;
    go.A[2] = AO; go.W[2] = Wob; go.bias[2] = bo; go.Out[2] = d_out; go.scl[2] = 1.0f; go.omode[2] = 2; go.af32[2] = 0;

    hipLaunchKernelGGL(cvt6_kernel, dim3(512, 6), dim3(256), 0, stream, ca);
    hipLaunchKernelGGL(gemm_k, dim3(32, 8, 3), dim3(512), 0, stream, gq);
    hipLaunchKernelGGL(attn_kernel, dim3(8, 64), dim3(256), 0, stream, Qh, Kh, Vt, AO);
    hipLaunchKernelGGL(gemm_k, dim3(32, 8, 1), dim3(512), 0, stream, go);
}

// Round 11
// 340.947 us; speedup vs baseline: 1.1435x; 1.0576x over previous
//
#include <hip/hip_runtime.h>
#include <hip/hip_bf16.h>

#define D_MODEL 1024
#define N_HEAD  16
#define HD      64
#define T_SEQ   2048
#define B_SZ    4
#define M_ROWS  (B_SZ * T_SEQ)   // 8192

typedef __bf16 bf16;
typedef __bf16 bf16x4 __attribute__((ext_vector_type(4)));
typedef __bf16 bf16x8 __attribute__((ext_vector_type(8)));
typedef float  floatx4 __attribute__((ext_vector_type(4)));

__device__ __forceinline__ floatx4 fzero4() {
    floatx4 z = {0.f, 0.f, 0.f, 0.f};
    return z;
}

__device__ __forceinline__ bf16x8 cvt8(const float4 a, const float4 b) {
    bf16x8 o;
    o[0] = (bf16)a.x; o[1] = (bf16)a.y; o[2] = (bf16)a.z; o[3] = (bf16)a.w;
    o[4] = (bf16)b.x; o[5] = (bf16)b.y; o[6] = (bf16)b.z; o[7] = (bf16)b.w;
    return o;
}

// async global->LDS, 16B/lane. LDS dest = wave-uniform base + lane*16.
__device__ __forceinline__ void async_ld16(const void* g, void* l) {
    __builtin_amdgcn_global_load_lds(
        (const __attribute__((address_space(1))) void*)g,
        (__attribute__((address_space(3))) void*)l,
        16, 0, 0);
}

// fused fp32 -> bf16 convert: 6 segments (q, k + 4 weights). v is consumed
// as fp32 directly by the V slice of the QKV GEMM (reg-staged cvt).
struct CvtArgs {
    const float* s[6];
    bf16* d[6];
    int n[6];
};
__global__ __launch_bounds__(256) void cvt6_kernel(CvtArgs a)
{
    const float* src = a.s[blockIdx.y];
    bf16* dst = a.d[blockIdx.y];
    int n8 = a.n[blockIdx.y];
    int i = blockIdx.x * blockDim.x + threadIdx.x;
    int stride = gridDim.x * blockDim.x;
    for (; i < n8; i += stride) {
        float4 x = ((const float4*)src)[2 * i];
        float4 y = ((const float4*)src)[2 * i + 1];
        ((bf16x8*)dst)[i] = cvt8(x, y);
    }
}

struct GemmArgs {
    const void* A[3];     // bf16 (af32=0) or fp32 (af32=1), [M,1024]
    const bf16* W[3];     // bf16 [N=1024,K=1024] (nn.Linear weight, row = out-feature)
    const float* bias[3];
    void*       Out[3];
    float       scl[3];
    int         omode[3]; // 0: bf16 [B,H,T,64]; 1: bf16 [B,H,64,T]; 2: fp32 [M,N]
    int         af32[3];  // 1: A is fp32, reg-staged with fused cvt
};

// QKV GEMM: C[8192,1024] = (A @ W^T + bias) * scl.  (verified R10: ~109 us
// for all 3 slices = 36 us/slice, best per-slice measured)
//  - 256x128 tile, 512 threads (8 waves, 4x2), single-buffered LDS,
//    2x __syncthreads per K-step.
//  - Q,K slices (af32=0): A via global_load_lds, pre-swizzled source.
//  - V slice (af32=1): A read fp32, reg-staged + fused cvt; hides under the
//    co-resident Q/K slices (768 blocks = 3/CU).
//  - Grid (32,8,z): A-sharing blocks same XCD (ids differ by 32 = 0 mod 8).
__global__ __launch_bounds__(512, 4) void gemm_k(GemmArgs g)
{
    __shared__ bf16 ldsA[256 * 64];   // 32 KB
    __shared__ bf16 ldsW[128 * 64];   // 16 KB

    const int z = blockIdx.z;
    const bf16* W     = g.W[z];
    const float* bias = g.bias[z];
    void* Out         = g.Out[z];
    const float scl   = g.scl[z];
    const int omode   = g.omode[z];
    const int af32    = g.af32[z];

    const int tid  = threadIdx.x;
    const int wave = tid >> 6, lane = tid & 63;   // wave 0..7
    const int quad = lane >> 4, l15 = lane & 15;
    const int wr = wave >> 1, wc = wave & 1;      // 4 x 2 wave grid
    const int m0 = blockIdx.x * 256, n0 = blockIdx.y * 128;

    floatx4 acc[4][4];
#pragma unroll
    for (int i = 0; i < 4; ++i)
#pragma unroll
        for (int j = 0; j < 4; ++j) acc[i][j] = fzero4();

    const int ro = lane >> 3;   // row-within-8
    const int c8 = lane & 7;    // chunk index

    // bf16 path: pre-swizzled global source, linear LDS dest (slot c holds chunk c^ro)
    const bf16* gAb = (const bf16*)g.A[z] + (size_t)(m0 + wave * 32 + ro) * 1024 + (c8 ^ ro) * 8;
    // fp32 path: linear global source, swizzled ds_write dest (same final layout)
    const float* gAf = (const float*)g.A[z] + (size_t)(m0 + wave * 32 + ro) * 1024 + c8 * 8;
    bf16* dA = &ldsA[(wave * 32 + ro) * 64 + (c8 ^ ro) * 8];

    const bf16* gW = W + (size_t)(n0 + wave * 16 + ro) * 1024 + (c8 ^ ro) * 8;

    float4 raf[4][2];
    if (af32) {
        // prologue: A(0) reg loads (latency exposed once)
#pragma unroll
        for (int j = 0; j < 4; ++j) {
            raf[j][0] = *(const float4*)(gAf + (size_t)j * 8192);
            raf[j][1] = *(const float4*)(gAf + (size_t)j * 8192 + 4);
        }
    }

    for (int kt = 0; kt < 16; ++kt) {
        __syncthreads();   // b1: prev-tile reads done; (af32: A regs drained by vmcnt(0))
        if (af32) {
#pragma unroll
            for (int j = 0; j < 4; ++j)
                *(bf16x8*)(dA + j * 8 * 64) = cvt8(raf[j][0], raf[j][1]);
        } else {
#pragma unroll
            for (int j = 0; j < 4; ++j)
                async_ld16((const void*)(gAb + kt * 64 + (size_t)j * 8 * 1024),
                           &ldsA[(wave * 32 + j * 8) * 64]);
        }
#pragma unroll
        for (int j = 0; j < 2; ++j)
            async_ld16((const void*)(gW + kt * 64 + (size_t)j * 8 * 1024),
                       &ldsW[(wave * 16 + j * 8) * 64]);
        __syncthreads();   // b2: vmcnt+lgkm drained -> tile visible

        // af32: issue next tile's A reg loads now; in flight under MFMA, drained at next b1
        if (af32 && kt < 15) {
            const int off = (kt + 1) * 64;
#pragma unroll
            for (int j = 0; j < 4; ++j) {
                raf[j][0] = *(const float4*)(gAf + off + (size_t)j * 8192);
                raf[j][1] = *(const float4*)(gAf + off + (size_t)j * 8192 + 4);
            }
        }

#pragma unroll
        for (int ks = 0; ks < 2; ++ks) {
            const int pos = ((ks * 4 + quad) ^ (l15 & 7)) * 8;
            bf16x8 af[4], bw[4];
#pragma unroll
            for (int i = 0; i < 4; ++i)
                af[i] = *(const bf16x8*)(&ldsA[(wr * 64 + i * 16 + l15) * 64 + pos]);
#pragma unroll
            for (int j = 0; j < 4; ++j)
                bw[j] = *(const bf16x8*)(&ldsW[(wc * 64 + j * 16 + l15) * 64 + pos]);
#pragma unroll
            for (int i = 0; i < 4; ++i)
#pragma unroll
                for (int j = 0; j < 4; ++j)
                    acc[i][j] = __builtin_amdgcn_mfma_f32_16x16x32_bf16(af[i], bw[j], acc[i][j], 0, 0, 0);
        }
    }

    // epilogue
#pragma unroll
    for (int i = 0; i < 4; ++i) {
#pragma unroll
        for (int j = 0; j < 4; ++j) {
            if (omode == 1) {
                // V^T out [B,H,64,T]: r -> t is contiguous; pack bf16x4 (8B stores)
                int m = m0 + wr * 64 + i * 16 + quad * 4;   // r=0
                int n = n0 + wc * 64 + j * 16 + l15;
                int b = m >> 11, t0 = m & 2047;
                int h = n >> 6,  d = n & 63;
                bf16x4 pv;
#pragma unroll
                for (int r = 0; r < 4; ++r)
                    pv[r] = (bf16)((acc[i][j][r] + bias[n]) * scl);
                size_t addr = ((size_t)(b * N_HEAD + h) * HD + d) * T_SEQ + t0;
                *(bf16x4*)(&((bf16*)Out)[addr]) = pv;
            } else {
#pragma unroll
                for (int r = 0; r < 4; ++r) {
                    int m = m0 + wr * 64 + i * 16 + quad * 4 + r;
                    int n = n0 + wc * 64 + j * 16 + l15;
                    float val = (acc[i][j][r] + bias[n]) * scl;
                    if (omode == 2) {
                        ((float*)Out)[(size_t)m * 1024 + n] = val;
                    } else {
                        int b = m >> 11, t = m & 2047;
                        int h = n >> 6,  d = n & 63;
                        size_t addr = ((size_t)(b * N_HEAD + h) * T_SEQ + t) * HD + d;
                        ((bf16*)Out)[addr] = (bf16)val;
                    }
                }
            }
        }
    }
}

// O-projection GEMM: Out[8192,1024] fp32 = AO @ Wo^T + bo.
// R0/R1-proven 128x128-tile / 256-thread / gload_lds structure. Separate from
// gemm_k because at grid (32,8) the 256x128 tile leaves 1 block/CU and the
// 2-barrier loop has nothing to overlap with (R9/R10: ~90-108 us). Grid (64,8)
// = 512 blocks = 2 blocks/CU; x = m-tile so A-sharing blocks (y=0..7) have ids
// differing by 64 = 0 mod 8 XCDs -> same XCD L2.
__global__ __launch_bounds__(256) void gemm_o(
    const bf16* __restrict__ A, const bf16* __restrict__ W,
    const float* __restrict__ bias, float* __restrict__ Out)
{
    __shared__ bf16 ldsA[128 * 64];   // 16 KB
    __shared__ bf16 ldsW[128 * 64];   // 16 KB

    const int tid  = threadIdx.x;
    const int wave = tid >> 6, lane = tid & 63;
    const int quad = lane >> 4, l15 = lane & 15;
    const int wr = wave >> 1, wc = wave & 1;
    const int m0 = blockIdx.x * 128, n0 = blockIdx.y * 128;

    floatx4 acc[4][4];
#pragma unroll
    for (int i = 0; i < 4; ++i)
#pragma unroll
        for (int j = 0; j < 4; ++j) acc[i][j] = fzero4();

    const int ro = lane >> 3;
    const int gc = (lane & 7) ^ ro;
    const bf16* gA = A + (size_t)(m0 + wave * 32 + ro) * 1024 + gc * 8;
    const bf16* gW = W + (size_t)(n0 + wave * 32 + ro) * 1024 + gc * 8;

    for (int kt = 0; kt < 16; ++kt) {
        __syncthreads();
#pragma unroll
        for (int j = 0; j < 4; ++j)
            async_ld16((const void*)(gA + kt * 64 + (size_t)j * 8 * 1024),
                       &ldsA[(wave * 32 + j * 8) * 64]);
#pragma unroll
        for (int j = 0; j < 4; ++j)
            async_ld16((const void*)(gW + kt * 64 + (size_t)j * 8 * 1024),
                       &ldsW[(wave * 32 + j * 8) * 64]);
        __syncthreads();

#pragma unroll
        for (int ks = 0; ks < 2; ++ks) {
            const int pos = ((ks * 4 + quad) ^ (l15 & 7)) * 8;
            bf16x8 af[4], bw[4];
#pragma unroll
            for (int i = 0; i < 4; ++i)
                af[i] = *(const bf16x8*)(&ldsA[(wr * 64 + i * 16 + l15) * 64 + pos]);
#pragma unroll
            for (int j = 0; j < 4; ++j)
                bw[j] = *(const bf16x8*)(&ldsW[(wc * 64 + j * 16 + l15) * 64 + pos]);
#pragma unroll
            for (int i = 0; i < 4; ++i)
#pragma unroll
                for (int j = 0; j < 4; ++j)
                    acc[i][j] = __builtin_amdgcn_mfma_f32_16x16x32_bf16(af[i], bw[j], acc[i][j], 0, 0, 0);
        }
    }

#pragma unroll
    for (int i = 0; i < 4; ++i)
#pragma unroll
        for (int j = 0; j < 4; ++j)
#pragma unroll
            for (int r = 0; r < 4; ++r) {
                int m = m0 + wr * 64 + i * 16 + quad * 4 + r;
                int n = n0 + wc * 64 + j * 16 + l15;
                Out[(size_t)m * 1024 + n] = acc[i][j][r] + bias[n];
            }
}

// Flash-style causal attention, S^T formulation, paired q-tiles for perfect balance.
// Qh (pre-scaled by 1/8*log2e), Kh: [B,H,T,64] bf16.  Vt: [B,H,64,T] bf16.  AO: [B,T,D] bf16.
// T14 async-STAGE split + T5 setprio + T13 defer-max (verified round 1: 110.9->91.5 us).
__global__ __launch_bounds__(256, 2) void attn_kernel(
    const bf16* __restrict__ Qh, const bf16* __restrict__ Kh,
    const bf16* __restrict__ Vt, bf16* __restrict__ AO)
{
    __shared__ bf16 Ks[128 * 64];   // 16 KB, XOR-swizzled chunks (slot c holds chunk c^(r&7))
    __shared__ bf16 Vts[64 * 128];  // 16 KB, XOR-swizzled (slot c holds chunk c^(d&15))
    __shared__ bf16 Ps[128 * 72];   // 18 KB, half-k P buffer (2-pass), wave-private rows

    const int tid  = threadIdx.x;
    const int wave = tid >> 6, lane = tid & 63;
    const int quad = lane >> 4, l15 = lane & 15;
    const int bh = blockIdx.y;
    const size_t base = (size_t)bh * T_SEQ * HD;
    const int bb = bh >> 4, hh = bh & 15;

    // staging lane->addr precompute (global source pre-swizzled, LDS dest swizzled slot)
    const int kro = lane >> 3;
    const int kgc = (lane & 7) ^ kro;
    const bf16* kgbase = Kh + base + (size_t)(wave * 32 + kro) * HD + kgc * 8;
    const int vrow_lo = lane >> 4;
    const int vchunk  = lane & 15;

    const bf16* vgbase[4];
    bf16* kdst[4];
    bf16* vdst[4];
#pragma unroll
    for (int j = 0; j < 4; ++j) {
        int d = wave * 16 + j * 4 + vrow_lo;
        int gcv = vchunk ^ (d & 15);
        vgbase[j] = Vt + base + (size_t)d * T_SEQ + gcv * 8;
        vdst[j]   = &Vts[d * 128 + vchunk * 8];
        kdst[j]   = &Ks[(wave * 32 + j * 8 + kro) * 64 + (lane & 7) * 8];
    }

    for (int phase = 0; phase < 2; ++phase) {
        const int qt = phase ? blockIdx.x : 15 - blockIdx.x;

        // Q fragments (pre-scaled), B-operand layout: lane l15 = q, k = quad*8+j
        bf16x8 qf[2][2];
        const bf16* qbase = Qh + base + (size_t)(qt * 128 + wave * 32) * HD;
#pragma unroll
        for (int ti = 0; ti < 2; ++ti)
#pragma unroll
            for (int ks = 0; ks < 2; ++ks)
                qf[ti][ks] = *(const bf16x8*)(qbase + (ti * 16 + l15) * HD + ks * 32 + quad * 8);

        // prologue: issue reg-loads for kt=0 (latency exposed once per phase)
        bf16x8 kreg[4], vreg[4];
#pragma unroll
        for (int j = 0; j < 4; ++j)
            kreg[j] = *(const bf16x8*)(kgbase + (size_t)(j * 8) * HD);
#pragma unroll
        for (int j = 0; j < 4; ++j)
            vreg[j] = *(const bf16x8*)(vgbase[j]);

        float mrow[2] = {-1e30f, -1e30f}, lrow[2] = {0.f, 0.f};
        floatx4 oacc[2][4];
#pragma unroll
        for (int ti = 0; ti < 2; ++ti)
#pragma unroll
            for (int nj = 0; nj < 4; ++nj) oacc[ti][nj] = fzero4();

        for (int kt = 0; kt <= qt; ++kt) {
            __syncthreads();   // all waves done reading Ks/Vts; vmcnt drain -> kreg/vreg ready
#pragma unroll
            for (int j = 0; j < 4; ++j) *(bf16x8*)kdst[j] = kreg[j];
#pragma unroll
            for (int j = 0; j < 4; ++j) *(bf16x8*)vdst[j] = vreg[j];
            __syncthreads();   // staged tile visible

            // T14: issue next tile's loads NOW; they complete under the compute below
            if (kt < qt) {
#pragma unroll
                for (int j = 0; j < 4; ++j)
                    kreg[j] = *(const bf16x8*)(kgbase + (size_t)((kt + 1) * 128 + j * 8) * HD);
#pragma unroll
                for (int j = 0; j < 4; ++j)
                    vreg[j] = *(const bf16x8*)(vgbase[j] + (kt + 1) * 128);
            }

            const bool diag = (kt == qt);
            const int lim = diag ? (2 * wave + 1) : 7;   // max tj with any unmasked k

            // S^T = K Q^T : A = K-frag (l15 = k-row), B = Q-frag (l15 = q)
            floatx4 sacc[2][8];
#pragma unroll
            for (int ti = 0; ti < 2; ++ti)
#pragma unroll
                for (int tj = 0; tj < 8; ++tj) sacc[ti][tj] = fzero4();
            __builtin_amdgcn_s_setprio(1);
#pragma unroll
            for (int ks = 0; ks < 2; ++ks) {
                const int pos = ((ks * 4 + quad) ^ (l15 & 7)) * 8;
#pragma unroll
                for (int tj = 0; tj < 8; ++tj) {
                    if (tj <= lim) {
                        bf16x8 kf = *(const bf16x8*)(&Ks[(tj * 16 + l15) * 64 + pos]);
                        sacc[0][tj] = __builtin_amdgcn_mfma_f32_16x16x32_bf16(kf, qf[0][ks], sacc[0][tj], 0, 0, 0);
                        sacc[1][tj] = __builtin_amdgcn_mfma_f32_16x16x32_bf16(kf, qf[1][ks], sacc[1][tj], 0, 0, 0);
                    }
                }
            }
            __builtin_amdgcn_s_setprio(0);

            // online softmax (scores pre-scaled): lane owns q = l15 (per ti)
#pragma unroll
            for (int ti = 0; ti < 2; ++ti) {
                const int ql = wave * 32 + ti * 16 + l15;
                float mxp[4] = {-1e30f, -1e30f, -1e30f, -1e30f};
#pragma unroll
                for (int tj = 0; tj < 8; ++tj) {
                    if (tj <= lim) {
#pragma unroll
                        for (int r = 0; r < 4; ++r) {
                            float s = sacc[ti][tj][r];
                            if (diag && (tj * 16 + quad * 4 + r) > ql) s = -1e30f;
                            sacc[ti][tj][r] = s;
                            mxp[r] = fmaxf(mxp[r], s);
                        }
                    }
                }
                float mx = fmaxf(fmaxf(mxp[0], mxp[1]), fmaxf(mxp[2], mxp[3]));
                mx = fmaxf(mx, __shfl_xor(mx, 16));
                mx = fmaxf(mx, __shfl_xor(mx, 32));
                // T13 defer-max: only rescale when some row's max grew by >8 (log2)
                if (__any(mx > mrow[ti] + 8.0f)) {
                    float mnew  = fmaxf(mrow[ti], mx);
                    float alpha = exp2f(mrow[ti] - mnew);
                    mrow[ti] = mnew;
                    lrow[ti] *= alpha;
#pragma unroll
                    for (int r = 0; r < 4; ++r) {
                        float ar = __shfl(alpha, quad * 4 + r);
#pragma unroll
                        for (int nj = 0; nj < 4; ++nj)
                            oacc[ti][nj][r] *= ar;
                    }
                }
                float rs[4] = {0.f, 0.f, 0.f, 0.f};
#pragma unroll
                for (int tj = 0; tj < 8; ++tj) {
                    if (tj <= lim) {
#pragma unroll
                        for (int r = 0; r < 4; ++r) {
                            float p = exp2f(sacc[ti][tj][r] - mrow[ti]);
                            rs[r] += p;
                            sacc[ti][tj][r] = p;
                        }
                    }
                }
                float rsum = (rs[0] + rs[1]) + (rs[2] + rs[3]);
                rsum += __shfl_xor(rsum, 16);
                rsum += __shfl_xor(rsum, 32);
                lrow[ti] += rsum;
            }

            // P -> LDS and O += P V, in two k-halves (Ps wave-private rows)
#pragma unroll
            for (int h2 = 0; h2 < 2; ++h2) {
                if (4 * h2 > lim) break;
#pragma unroll
                for (int ti = 0; ti < 2; ++ti) {
                    const int ql = wave * 32 + ti * 16 + l15;
#pragma unroll
                    for (int tjo = 0; tjo < 4; ++tjo) {
                        int tj = 4 * h2 + tjo;
                        if (tj <= lim) {
                            bf16x4 pv;
#pragma unroll
                            for (int r = 0; r < 4; ++r) pv[r] = (bf16)sacc[ti][tj][r];
                            *(bf16x4*)(&Ps[ql * 72 + tjo * 16 + quad * 4]) = pv;
                        }
                    }
                }
#pragma unroll
                for (int ks2 = 0; ks2 < 2; ++ks2) {
                    const int gks = 2 * h2 + ks2;
                    if (diag && gks > wave) break;
                    bf16x8 pf[2];
                    pf[0] = *(const bf16x8*)(&Ps[(wave * 32 + l15) * 72 + ks2 * 32 + quad * 8]);
                    pf[1] = *(const bf16x8*)(&Ps[(wave * 32 + 16 + l15) * 72 + ks2 * 32 + quad * 8]);
                    __builtin_amdgcn_s_setprio(1);
#pragma unroll
                    for (int nj = 0; nj < 4; ++nj) {
                        int pos = ((gks * 4 + quad) ^ l15) * 8;
                        bf16x8 vf = *(const bf16x8*)(&Vts[(nj * 16 + l15) * 128 + pos]);
                        oacc[0][nj] = __builtin_amdgcn_mfma_f32_16x16x32_bf16(pf[0], vf, oacc[0][nj], 0, 0, 0);
                        oacc[1][nj] = __builtin_amdgcn_mfma_f32_16x16x32_bf16(pf[1], vf, oacc[1][nj], 0, 0, 0);
                    }
                    __builtin_amdgcn_s_setprio(0);
                }
            }
        }

        // epilogue: O /= l ; O rows = quad*4+r, cols d = nj*16+l15
#pragma unroll
        for (int ti = 0; ti < 2; ++ti) {
#pragma unroll
            for (int r = 0; r < 4; ++r) {
                float lv = __shfl(lrow[ti], quad * 4 + r);
                float rl = 1.f / lv;
                int qrow = qt * 128 + wave * 32 + ti * 16 + quad * 4 + r;
#pragma unroll
                for (int nj = 0; nj < 4; ++nj) {
                    int d = nj * 16 + l15;
                    AO[((size_t)(bb * T_SEQ + qrow)) * D_MODEL + hh * HD + d] =
                        (bf16)(oacc[ti][nj][r] * rl);
                }
            }
        }
    }
}

extern "C" void kernel_launch(void* const* d_in, const int* in_sizes, int n_in,
                              void* d_out, int out_size, void* d_ws, size_t ws_size,
                              hipStream_t stream)
{
    const float* q  = (const float*)d_in[0];
    const float* k  = (const float*)d_in[1];
    const float* v  = (const float*)d_in[2];
    const float* wq = (const float*)d_in[3];
    const float* bq = (const float*)d_in[4];
    const float* wk = (const float*)d_in[5];
    const float* bk = (const float*)d_in[6];
    const float* wv = (const float*)d_in[7];
    const float* bv = (const float*)d_in[8];
    const float* wo = (const float*)d_in[9];
    const float* bo = (const float*)d_in[10];

    char* ws  = (char*)d_ws;
    char* dob = (char*)d_out;
    const size_t MB = 1024 * 1024;

    // ws (56 MB): Wqb[0,2) Wkb[2,4) Wvb[4,6) Wob[6,8) Qb[8,24) Kb[24,40) Vt[40,56)
    //   AO overwrites Qb's region [8,24) after the QKV GEMM consumed Qb.
    // d_out (32 MB): Qh[0,16) Kh[16,32) bf16 during attn, then final fp32 out
    //   (O-GEMM overwrites after attn consumed Qh/Kh).
    bf16* Wqb = (bf16*)(ws);
    bf16* Wkb = (bf16*)(ws + 2 * MB);
    bf16* Wvb = (bf16*)(ws + 4 * MB);
    bf16* Wob = (bf16*)(ws + 6 * MB);
    bf16* Qb  = (bf16*)(ws + 8 * MB);
    bf16* AO  = (bf16*)(ws + 8 * MB);
    bf16* Kb  = (bf16*)(ws + 24 * MB);
    bf16* Vt  = (bf16*)(ws + 40 * MB);
    bf16* Qh  = (bf16*)(dob);
    bf16* Kh  = (bf16*)(dob + 16 * MB);

    const int NQ8 = M_ROWS * D_MODEL / 8;   // 1M
    const int NW8 = D_MODEL * D_MODEL / 8;  // 128K
    const float QSCALE = 0.18033688011112042f;  // (1/sqrt(64)) * log2(e)

    CvtArgs ca;
    ca.s[0] = q;  ca.d[0] = Qb;  ca.n[0] = NQ8;
    ca.s[1] = k;  ca.d[1] = Kb;  ca.n[1] = NQ8;
    ca.s[2] = wq; ca.d[2] = Wqb; ca.n[2] = NW8;
    ca.s[3] = wk; ca.d[3] = Wkb; ca.n[3] = NW8;
    ca.s[4] = wv; ca.d[4] = Wvb; ca.n[4] = NW8;
    ca.s[5] = wo; ca.d[5] = Wob; ca.n[5] = NW8;

    GemmArgs gq;
    gq.A[0] = Qb; gq.W[0] = Wqb; gq.bias[0] = bq; gq.Out[0] = (void*)Qh; gq.scl[0] = QSCALE; gq.omode[0] = 0; gq.af32[0] = 0;
    gq.A[1] = Kb; gq.W[1] = Wkb; gq.bias[1] = bk; gq.Out[1] = (void*)Kh; gq.scl[1] = 1.0f;   gq.omode[1] = 0; gq.af32[1] = 0;
    gq.A[2] = v;  gq.W[2] = Wvb; gq.bias[2] = bv; gq.Out[2] = (void*)Vt; gq.scl[2] = 1.0f;   gq.omode[2] = 1; gq.af32[2] = 1;

    hipLaunchKernelGGL(cvt6_kernel, dim3(512, 6), dim3(256), 0, stream, ca);
    hipLaunchKernelGGL(gemm_k, dim3(32, 8, 3), dim3(512), 0, stream, gq);
    hipLaunchKernelGGL(attn_kernel, dim3(8, 64), dim3(256), 0, stream, Qh, Kh, Vt, AO);
    hipLaunchKernelGGL(gemm_o, dim3(64, 8), dim3(256), 0, stream, AO, Wob, bo, (float*)d_out);
}